// Round 6
// baseline (26.076 us; speedup 1.0000x reference)
//
#include <hip/hip_runtime.h>
#include <hip/hip_bf16.h>
#include <math.h>

#define EPS 1e-10f
#define LOG2E 1.4426950408889634f

typedef float floatx4 __attribute__((ext_vector_type(4)));

// One block per row, 1024 threads (16 waves), contiguous row streaming.
// Scores (monotone-equivalent to reference's softmax(l/t)/(E+eps)):
//   greedy (t==0): l[j]
//   sampled:       l[j]*(log2e/t) - log2(E[j]+EPS)   [v_log_f32, 1 inst]
// Unroll x2 with dual accumulators: 4 loads in flight per wave, split
// cndmask dependency chains. First-occurrence tie-break == jnp.argmax.
__global__ __launch_bounds__(1024) void sampler_row_kernel(
    const float* __restrict__ logits,
    const float* __restrict__ temps,
    const float* __restrict__ expo,
    int* __restrict__ out, int V) {

    const int row = blockIdx.x;
    const float t = temps[row];                  // block-uniform
    const bool greedy = (t == 0.0f);
    const float c = greedy ? 1.0f : (LOG2E / t);

    const float*   rl  = logits + (size_t)row * (size_t)V;
    const floatx4* rl4 = reinterpret_cast<const floatx4*>(rl);
    const floatx4* e4  = reinterpret_cast<const floatx4*>(expo);

    float best0 = -INFINITY, best1 = -INFINITY;
    int   bidx0 = 0x7fffffff, bidx1 = 0x7fffffff;

    const int nvec = V >> 2;
    int i = threadIdx.x;

    if (greedy) {
        for (; i + 1024 < nvec; i += 2048) {
            floatx4 a = rl4[i];
            floatx4 b = rl4[i + 1024];
            int ab = i << 2, bb = (i + 1024) << 2;
            if (a.x > best0) { best0 = a.x; bidx0 = ab;     }
            if (a.y > best0) { best0 = a.y; bidx0 = ab + 1; }
            if (a.z > best0) { best0 = a.z; bidx0 = ab + 2; }
            if (a.w > best0) { best0 = a.w; bidx0 = ab + 3; }
            if (b.x > best1) { best1 = b.x; bidx1 = bb;     }
            if (b.y > best1) { best1 = b.y; bidx1 = bb + 1; }
            if (b.z > best1) { best1 = b.z; bidx1 = bb + 2; }
            if (b.w > best1) { best1 = b.w; bidx1 = bb + 3; }
        }
        for (; i < nvec; i += 1024) {
            floatx4 a = rl4[i];
            int ab = i << 2;
            if (a.x > best0) { best0 = a.x; bidx0 = ab;     }
            if (a.y > best0) { best0 = a.y; bidx0 = ab + 1; }
            if (a.z > best0) { best0 = a.z; bidx0 = ab + 2; }
            if (a.w > best0) { best0 = a.w; bidx0 = ab + 3; }
        }
    } else {
        for (; i + 1024 < nvec; i += 2048) {
            floatx4 a  = rl4[i];
            floatx4 b  = rl4[i + 1024];
            floatx4 ea = e4[i];
            floatx4 eb = e4[i + 1024];
            int ab = i << 2, bb = (i + 1024) << 2;
            float s;
            s = fmaf(a.x, c, -__builtin_amdgcn_logf(ea.x + EPS)); if (s > best0) { best0 = s; bidx0 = ab;     }
            s = fmaf(a.y, c, -__builtin_amdgcn_logf(ea.y + EPS)); if (s > best0) { best0 = s; bidx0 = ab + 1; }
            s = fmaf(a.z, c, -__builtin_amdgcn_logf(ea.z + EPS)); if (s > best0) { best0 = s; bidx0 = ab + 2; }
            s = fmaf(a.w, c, -__builtin_amdgcn_logf(ea.w + EPS)); if (s > best0) { best0 = s; bidx0 = ab + 3; }
            s = fmaf(b.x, c, -__builtin_amdgcn_logf(eb.x + EPS)); if (s > best1) { best1 = s; bidx1 = bb;     }
            s = fmaf(b.y, c, -__builtin_amdgcn_logf(eb.y + EPS)); if (s > best1) { best1 = s; bidx1 = bb + 1; }
            s = fmaf(b.z, c, -__builtin_amdgcn_logf(eb.z + EPS)); if (s > best1) { best1 = s; bidx1 = bb + 2; }
            s = fmaf(b.w, c, -__builtin_amdgcn_logf(eb.w + EPS)); if (s > best1) { best1 = s; bidx1 = bb + 3; }
        }
        for (; i < nvec; i += 1024) {
            floatx4 a  = rl4[i];
            floatx4 ea = e4[i];
            int ab = i << 2;
            float s;
            s = fmaf(a.x, c, -__builtin_amdgcn_logf(ea.x + EPS)); if (s > best0) { best0 = s; bidx0 = ab;     }
            s = fmaf(a.y, c, -__builtin_amdgcn_logf(ea.y + EPS)); if (s > best0) { best0 = s; bidx0 = ab + 1; }
            s = fmaf(a.z, c, -__builtin_amdgcn_logf(ea.z + EPS)); if (s > best0) { best0 = s; bidx0 = ab + 2; }
            s = fmaf(a.w, c, -__builtin_amdgcn_logf(ea.w + EPS)); if (s > best0) { best0 = s; bidx0 = ab + 3; }
        }
    }

    // Merge dual accumulators (both subsequences ascend; prefer lower index).
    float best = best0;
    int   bidx = bidx0;
    if (best1 > best || (best1 == best && bidx1 < bidx)) { best = best1; bidx = bidx1; }

    // Scalar tail (V % 4 != 0); zero iterations for V = 128000.
    for (int j = (nvec << 2) + threadIdx.x; j < V; j += 1024) {
        float s = greedy ? rl[j]
                         : fmaf(rl[j], c, -__builtin_amdgcn_logf(expo[j] + EPS));
        if (s > best) { best = s; bidx = j; }
    }

    // Wave reduce (64 lanes on CDNA). Prefer lower index on exact ties.
    #pragma unroll
    for (int off = 32; off >= 1; off >>= 1) {
        float ov = __shfl_down(best, off);
        int   oi = __shfl_down(bidx, off);
        if (ov > best || (ov == best && oi < bidx)) { best = ov; bidx = oi; }
    }

    // Cross-wave reduce via LDS (16 waves).
    __shared__ float sv[16];
    __shared__ int   si[16];
    const int wid  = threadIdx.x >> 6;
    const int lane = threadIdx.x & 63;
    if (lane == 0) { sv[wid] = best; si[wid] = bidx; }
    __syncthreads();

    if (wid == 0) {
        best = (lane < 16) ? sv[lane] : -INFINITY;
        bidx = (lane < 16) ? si[lane] : 0x7fffffff;
        #pragma unroll
        for (int off = 8; off >= 1; off >>= 1) {
            float ov = __shfl_down(best, off);
            int   oi = __shfl_down(bidx, off);
            if (ov > best || (ov == best && oi < bidx)) { best = ov; bidx = oi; }
        }
        if (lane == 0) out[row] = bidx;
    }
}

extern "C" void kernel_launch(void* const* d_in, const int* in_sizes, int n_in,
                              void* d_out, int out_size, void* d_ws, size_t ws_size,
                              hipStream_t stream) {
    const float* logits = (const float*)d_in[0];
    const float* temps  = (const float*)d_in[1];
    const float* expo   = (const float*)d_in[2];
    int*         out    = (int*)d_out;

    const int B = in_sizes[1];
    const int V = in_sizes[2];

    sampler_row_kernel<<<B, 1024, 0, stream>>>(logits, temps, expo, out, V);
}